// Round 2
// baseline (591.249 us; speedup 1.0000x reference)
//
#include <hip/hip_runtime.h>
#include <math.h>

// Problem constants (from reference setup): T=4, B=64, N=1024, P=63, D=128
#define T_STEPS 4
#define R_ROWS  65536              // B*N rows per timestep
#define M_ROWS  262144             // T*B*N total rows
#define P_DIM   63
#define D_DIM   128
#define PP      64                 // padded P (col 63 = virtual ones column in K1)

#define TILES_TOTAL (M_ROWS / 64)  // 4096 tiles of 64 rows
#define G_CHUNKS 8                 // reduce output copies consumed by stats

typedef float v4f __attribute__((ext_vector_type(4)));

// ---------------------------------------------------------------------------
// K1: per-block partial Gram  P_b = xa_b^T xa_b  (xa = x + ones column).
// (unchanged in r12 — isolate the K3 rewrite for clean attribution)
// ---------------------------------------------------------------------------
__global__ __launch_bounds__(256) void gram_kernel(const float* __restrict__ x,
                                                   double* __restrict__ partials,
                                                   int tiles_per_block) {
    __shared__ __align__(16) float xt[2][64 * PP];
    const int tid = threadIdx.x;
    const int tj = tid & 15;       // 16 col-tiles of 4
    const int ti = tid >> 4;       // 16 row-tiles of 4

    double dacc[4][4];
#pragma unroll
    for (int a = 0; a < 4; a++)
#pragma unroll
        for (int b = 0; b < 4; b++) dacc[a][b] = 0.0;

    if (tid < 64) {                // ones column in both buffers (never overwritten)
        xt[0][tid * PP + 63] = 1.0f;
        xt[1][tid * PP + 63] = 1.0f;
    }

    const int tile0 = blockIdx.x * tiles_per_block;
    float4 reg[4];

    {
        const float4* src = (const float4*)(x + (size_t)tile0 * (64 * 63));
#pragma unroll
        for (int it = 0; it < 4; it++) {
            int k = tid + it * 256;
            reg[it] = (k < 1008) ? src[k] : make_float4(0.f, 0.f, 0.f, 0.f);
        }
    }
#pragma unroll
    for (int it = 0; it < 4; it++) {
        int k = tid + it * 256;
        if (k < 1008) {
            const float* ve = (const float*)&reg[it];
            int flat = k * 4;
#pragma unroll
            for (int e = 0; e < 4; e++) {
                int f = flat + e;
                int r = f / 63;
                int c = f - r * 63;
                xt[0][r * PP + c] = ve[e];
            }
        }
    }
    __syncthreads();

    for (int t = 0; t < tiles_per_block; t++) {
        const int cur = t & 1;
        if (t + 1 < tiles_per_block) {
            const float4* src = (const float4*)(x + (size_t)(tile0 + t + 1) * (64 * 63));
#pragma unroll
            for (int it = 0; it < 4; it++) {
                int k = tid + it * 256;
                reg[it] = (k < 1008) ? src[k] : make_float4(0.f, 0.f, 0.f, 0.f);
            }
        }

        float facc[4][4];
#pragma unroll
        for (int a = 0; a < 4; a++)
#pragma unroll
            for (int b = 0; b < 4; b++) facc[a][b] = 0.0f;

        const float* buf = xt[cur];
        for (int r = 0; r < 64; r++) {
            float4 xi = *(const float4*)&buf[r * PP + ti * 4];
            float4 xj = *(const float4*)&buf[r * PP + tj * 4];
            const float* xia = (const float*)&xi;
            const float* xja = (const float*)&xj;
#pragma unroll
            for (int a = 0; a < 4; a++)
#pragma unroll
                for (int b = 0; b < 4; b++)
                    facc[a][b] = fmaf(xia[a], xja[b], facc[a][b]);
        }
#pragma unroll
        for (int a = 0; a < 4; a++)
#pragma unroll
            for (int b = 0; b < 4; b++) dacc[a][b] += (double)facc[a][b];

        __syncthreads();
        if (t + 1 < tiles_per_block) {
            float* nbuf = xt[1 - cur];
#pragma unroll
            for (int it = 0; it < 4; it++) {
                int k = tid + it * 256;
                if (k < 1008) {
                    const float* ve = (const float*)&reg[it];
                    int flat = k * 4;
#pragma unroll
                    for (int e = 0; e < 4; e++) {
                        int f = flat + e;
                        int r = f / 63;
                        int c = f - r * 63;
                        nbuf[r * PP + c] = ve[e];
                    }
                }
            }
            __syncthreads();
        }
    }

    double* Pb = partials + (size_t)blockIdx.x * 4096;
#pragma unroll
    for (int a = 0; a < 4; a++)
#pragma unroll
        for (int b = 0; b < 4; b++)
            Pb[(ti * 4 + a) * 64 + (tj * 4 + b)] = dacc[a][b];
}

// ---------------------------------------------------------------------------
// K1b: fold nparts partials into G_CHUNKS copies (deterministic fp64 sums).
// Blocks >= 128 instead build Wp[d*64+p] = W[d*63+p] (p<63, else 0) — the
// p-padded row-major W used by lif's wave-uniform scalar loads.
// ---------------------------------------------------------------------------
__global__ __launch_bounds__(256) void reduce_kernel(const double* __restrict__ partials,
                                                     double* __restrict__ G8,
                                                     const float* __restrict__ W,
                                                     float* __restrict__ Wp,
                                                     int copies_per_chunk) {
    if (blockIdx.x >= G_CHUNKS * 16) {
        int widx = (blockIdx.x - G_CHUNKS * 16) * 256 + threadIdx.x;
        for (int j = widx; j < D_DIM * 64; j += 8 * 256) {
            int d = j >> 6;
            int p = j & 63;
            Wp[j] = (p < P_DIM) ? W[d * P_DIM + p] : 0.0f;
        }
        return;
    }
    const int chunk = blockIdx.x >> 4;             // 0..7
    const int idx   = (blockIdx.x & 15) * 256 + threadIdx.x;  // 0..4095
    const double* src = partials + (size_t)chunk * copies_per_chunk * 4096;
    double s = 0.0;
    for (int c = 0; c < copies_per_chunk; c++)
        s += src[(size_t)c * 4096 + idx];
    G8[(size_t)chunk * 4096 + idx] = s;
}

// ---------------------------------------------------------------------------
// K2: per-channel stats (unchanged).
// ---------------------------------------------------------------------------
__global__ __launch_bounds__(64) void stats_kernel(const double* __restrict__ G,
                                                   const float* __restrict__ W,
                                                   const float* __restrict__ gamma,
                                                   const float* __restrict__ beta,
                                                   float* __restrict__ stats) {
    const int d = blockIdx.x;    // 0..127
    const int p = threadIdx.x;   // 0..63
    __shared__ float sW[64];
    sW[p] = (p < P_DIM) ? W[d * P_DIM + p] : 0.0f;
    __syncthreads();

    double inner = 0.0;
#pragma unroll
    for (int c = 0; c < G_CHUNKS; c++) {
        const double* Gr = G + (size_t)c * (64 * 64) + p * 64;
        for (int q = 0; q < 64; q++) inner += Gr[q] * (double)sW[q];
    }

    double contrib = (double)sW[p] * inner;   // row 63 has w=0 -> no effect
    double ex2M = contrib;
#pragma unroll
    for (int off = 32; off > 0; off >>= 1) ex2M += __shfl_down(ex2M, off, 64);
    double meanM = __shfl(inner, 63, 64);     // ones-row dot W_d = colsum . W_d

    if (p == 0) {
        double mean = meanM / (double)M_ROWS;
        double ex2  = ex2M  / (double)M_ROWS;
        double var  = ex2 - mean * mean;
        float varf  = (float)var;
        float vpe   = varf + 1e-5f;                 // ref: fp32 var + fp32 eps
        float invstd = (float)(1.0 / sqrt((double)vpe));
        stats[d * 4 + 0] = (float)mean;
        stats[d * 4 + 1] = invstd;
        stats[d * 4 + 2] = gamma[d];
        stats[d * 4 + 3] = beta[d];
    }
}

// ---------------------------------------------------------------------------
// K3 r12: W OFF THE LDS PIPE.  r11 post-mortem: 9.1M bank-conflict cycles +
// 16 b128/256 FMA kept the per-CU LDS pipe as critical path (~55-60us vs
// 27us FMA floor).  New decomposition:
//   lane = row (64 rows/block), wave = channel chunk (d0 = wave*32).
//   W reads are WAVE-UNIFORM (readfirstlane'd wave id) -> scalar/L1-broadcast
//   loads on the scalar/VMEM pipes, zero LDS, SGPR operand into v_fma.
//   x staged once: sx[t][row][64] with 16B XOR swizzle (quad ^= row&7):
//   ds_read_b128 per (t,pq) = 8 lanes/bank-group = minimum, conflict-free.
//   Per wave: 64 x-b128 reads feed 8192 FMAs (1:128).
// p padded to 64 (x pad=0, Wp pad=0): fmaf(0,0,acc)==acc exactly -> the
// per-acc fmaf chain is still ascending p=0..62 -> h bitwise identical.
// acc[4][32]=128 VGPR; LDS 65536B -> 2 blocks/CU; launch_bounds(256,2).
// ---------------------------------------------------------------------------
__global__ __launch_bounds__(256, 2) void lif_kernel(const float* __restrict__ x,
                                                     const float* __restrict__ Wp,
                                                     const float* __restrict__ stats,
                                                     float* __restrict__ out) {
    __shared__ __align__(16) float sx[T_STEPS * 64 * 64];   // 65536 B
    const int tid = threadIdx.x;
    const int seg = tid >> 6;          // timestep handled during staging
    const int lane = tid & 63;

    // zero the padded column c=63 for (t=seg, r=lane); quad 15, swizzled
    sx[(seg * 64 + lane) * 64 + (((15 ^ (lane & 7)) << 2) | 3)] = 0.0f;

    // stage x rows r0..r0+63, all 4 timesteps: coalesced b128 + swizzled scatter
    const int r0 = blockIdx.x * 64;
    const v4f* src = (const v4f*)(x + ((size_t)seg * R_ROWS + r0) * P_DIM);
#pragma unroll
    for (int kk = 0; kk < 16; kk++) {
        int k = lane + kk * 64;        // 0..1023; 1008 = 64*63/4 valid
        v4f v;
        if (k < 1008) v = __builtin_nontemporal_load(&src[k]);
        if (k < 1008) {
            int flat = k * 4;
#pragma unroll
            for (int e = 0; e < 4; e++) {
                int f = flat + e;
                int r = f / 63;
                int c = f - r * 63;
                sx[(seg * 64 + r) * 64 + ((((c >> 2) ^ (r & 7)) << 2) | (c & 3))] = v[e];
            }
        }
    }
    __syncthreads();

    // wave-uniform channel chunk
    const int wv = __builtin_amdgcn_readfirstlane(tid >> 6);
    const int d0 = wv * 32;
    const float* __restrict__ wbase = Wp + (size_t)d0 * 64;
    const int s7 = lane & 7;

    float acc[T_STEPS][32];
#pragma unroll
    for (int t = 0; t < T_STEPS; t++)
#pragma unroll
        for (int c = 0; c < 32; c++) acc[t][c] = 0.0f;

    // main loop over 16 p-quads (p = 0..63, quad 15 is the exact no-op pad)
#pragma unroll 2
    for (int pq = 0; pq < 16; pq++) {
        float4 xq[T_STEPS];
#pragma unroll
        for (int t = 0; t < T_STEPS; t++)
            xq[t] = *(const float4*)&sx[(t * 64 + lane) * 64 + ((pq ^ s7) << 2)];

#pragma unroll
        for (int c = 0; c < 32; c++) {
            float4 w = *(const float4*)&wbase[c * 64 + (pq << 2)];  // uniform
            const float* wa = (const float*)&w;
#pragma unroll
            for (int pp = 0; pp < 4; pp++) {         // ascending p within quad
                const float wval = wa[pp];
#pragma unroll
                for (int t = 0; t < T_STEPS; t++) {
                    const float xval = ((const float*)&xq[t])[pp];
                    acc[t][c] = fmaf(xval, wval, acc[t][c]);
                }
            }
        }
    }

    // epilogue: BN affine (ref op order) + LIF scan; per channel-quad to keep
    // live registers bounded; nontemporal b128 stores
    const int rowg = r0 + lane;
#pragma unroll
    for (int jq = 0; jq < 8; jq++) {
        v4f o[T_STEPS];
#pragma unroll
        for (int j4 = 0; j4 < 4; j4++) {
            const int c = jq * 4 + j4;
            float4 st = ((const float4*)stats)[d0 + c];  // mean, invstd, gamma, beta
            float v = 0.0f;
#pragma unroll
            for (int t = 0; t < T_STEPS; t++) {
                float hn = (acc[t][c] - st.x) * st.y;
                hn = hn * st.z;
                hn = hn + st.w;
                v = v + (hn - v) * 0.5f;       // == v + (x-v)/2, exact
                float s = (v >= 1.0f) ? 1.0f : 0.0f;  // (v-1>=0) sign-exact
                o[t][j4] = s;
                if (s != 0.0f) v = 0.0f;       // hard reset
            }
        }
#pragma unroll
        for (int t = 0; t < T_STEPS; t++)
            __builtin_nontemporal_store(
                o[t], (v4f*)&out[((size_t)t * R_ROWS + rowg) * D_DIM + d0 + jq * 4]);
    }
}

// ---------------------------------------------------------------------------
extern "C" void kernel_launch(void* const* d_in, const int* in_sizes, int n_in,
                              void* d_out, int out_size, void* d_ws, size_t ws_size,
                              hipStream_t stream) {
    const float* x     = (const float*)d_in[0];
    const float* W     = (const float*)d_in[1];
    const float* gamma = (const float*)d_in[2];
    const float* beta  = (const float*)d_in[3];
    float* out = (float*)d_out;

    // pick partial count by available workspace (power of 2, 64..512)
    const size_t fixed = (size_t)G_CHUNKS * 4096 * 8 + 2048 + 32768 + 4096;
    int nparts = 512;
    while (nparts > 64 && (size_t)nparts * 4096 * 8 + fixed > ws_size) nparts >>= 1;
    const int tiles_per_block = TILES_TOTAL / nparts;

    double* partials = (double*)d_ws;
    double* G8       = (double*)((char*)d_ws + (size_t)nparts * 4096 * 8);
    float*  stats    = (float*)((char*)G8 + (size_t)G_CHUNKS * 4096 * 8);
    float*  Wp       = (float*)((char*)stats + 2048);

    gram_kernel<<<nparts, 256, 0, stream>>>(x, partials, tiles_per_block);
    reduce_kernel<<<G_CHUNKS * 16 + 8, 256, 0, stream>>>(partials, G8, W, Wp,
                                                         nparts / G_CHUNKS);
    stats_kernel<<<D_DIM, 64, 0, stream>>>(G8, W, gamma, beta, stats);
    lif_kernel<<<R_ROWS / 64, 256, 0, stream>>>(x, Wp, stats, out);
}

// Round 4
// 333.511 us; speedup vs baseline: 1.7728x; 1.7728x over previous
//
#include <hip/hip_runtime.h>
#include <math.h>

// Problem constants (from reference setup): T=4, B=64, N=1024, P=63, D=128
#define T_STEPS 4
#define R_ROWS  65536              // B*N rows per timestep
#define M_ROWS  262144             // T*B*N total rows
#define P_DIM   63
#define D_DIM   128
#define PP      64                 // padded P (col 63 = virtual ones column in K1)

#define TILES_TOTAL (M_ROWS / 64)  // 4096 tiles of 64 rows
#define G_CHUNKS 8                 // reduce output copies consumed by stats

typedef float v4f __attribute__((ext_vector_type(4)));

// ---------------------------------------------------------------------------
// K1: per-block partial Gram  P_b = xa_b^T xa_b  (xa = x + ones column).
// (unchanged — isolate the K3 fix for clean attribution)
// ---------------------------------------------------------------------------
__global__ __launch_bounds__(256) void gram_kernel(const float* __restrict__ x,
                                                   double* __restrict__ partials,
                                                   int tiles_per_block) {
    __shared__ __align__(16) float xt[2][64 * PP];
    const int tid = threadIdx.x;
    const int tj = tid & 15;       // 16 col-tiles of 4
    const int ti = tid >> 4;       // 16 row-tiles of 4

    double dacc[4][4];
#pragma unroll
    for (int a = 0; a < 4; a++)
#pragma unroll
        for (int b = 0; b < 4; b++) dacc[a][b] = 0.0;

    if (tid < 64) {                // ones column in both buffers (never overwritten)
        xt[0][tid * PP + 63] = 1.0f;
        xt[1][tid * PP + 63] = 1.0f;
    }

    const int tile0 = blockIdx.x * tiles_per_block;
    float4 reg[4];

    {
        const float4* src = (const float4*)(x + (size_t)tile0 * (64 * 63));
#pragma unroll
        for (int it = 0; it < 4; it++) {
            int k = tid + it * 256;
            reg[it] = (k < 1008) ? src[k] : make_float4(0.f, 0.f, 0.f, 0.f);
        }
    }
#pragma unroll
    for (int it = 0; it < 4; it++) {
        int k = tid + it * 256;
        if (k < 1008) {
            const float* ve = (const float*)&reg[it];
            int flat = k * 4;
#pragma unroll
            for (int e = 0; e < 4; e++) {
                int f = flat + e;
                int r = f / 63;
                int c = f - r * 63;
                xt[0][r * PP + c] = ve[e];
            }
        }
    }
    __syncthreads();

    for (int t = 0; t < tiles_per_block; t++) {
        const int cur = t & 1;
        if (t + 1 < tiles_per_block) {
            const float4* src = (const float4*)(x + (size_t)(tile0 + t + 1) * (64 * 63));
#pragma unroll
            for (int it = 0; it < 4; it++) {
                int k = tid + it * 256;
                reg[it] = (k < 1008) ? src[k] : make_float4(0.f, 0.f, 0.f, 0.f);
            }
        }

        float facc[4][4];
#pragma unroll
        for (int a = 0; a < 4; a++)
#pragma unroll
            for (int b = 0; b < 4; b++) facc[a][b] = 0.0f;

        const float* buf = xt[cur];
        for (int r = 0; r < 64; r++) {
            float4 xi = *(const float4*)&buf[r * PP + ti * 4];
            float4 xj = *(const float4*)&buf[r * PP + tj * 4];
            const float* xia = (const float*)&xi;
            const float* xja = (const float*)&xj;
#pragma unroll
            for (int a = 0; a < 4; a++)
#pragma unroll
                for (int b = 0; b < 4; b++)
                    facc[a][b] = fmaf(xia[a], xja[b], facc[a][b]);
        }
#pragma unroll
        for (int a = 0; a < 4; a++)
#pragma unroll
            for (int b = 0; b < 4; b++) dacc[a][b] += (double)facc[a][b];

        __syncthreads();
        if (t + 1 < tiles_per_block) {
            float* nbuf = xt[1 - cur];
#pragma unroll
            for (int it = 0; it < 4; it++) {
                int k = tid + it * 256;
                if (k < 1008) {
                    const float* ve = (const float*)&reg[it];
                    int flat = k * 4;
#pragma unroll
                    for (int e = 0; e < 4; e++) {
                        int f = flat + e;
                        int r = f / 63;
                        int c = f - r * 63;
                        nbuf[r * PP + c] = ve[e];
                    }
                }
            }
            __syncthreads();
        }
    }

    double* Pb = partials + (size_t)blockIdx.x * 4096;
#pragma unroll
    for (int a = 0; a < 4; a++)
#pragma unroll
        for (int b = 0; b < 4; b++)
            Pb[(ti * 4 + a) * 64 + (tj * 4 + b)] = dacc[a][b];
}

// ---------------------------------------------------------------------------
// K1b: fold nparts partials into G_CHUNKS copies (deterministic fp64 sums).
// Blocks >= 128 instead build Wp[d*64+p] = W[d*63+p] (p<63, else 0) — the
// p-padded row-major W used by lif's wave-uniform loads.
// ---------------------------------------------------------------------------
__global__ __launch_bounds__(256) void reduce_kernel(const double* __restrict__ partials,
                                                     double* __restrict__ G8,
                                                     const float* __restrict__ W,
                                                     float* __restrict__ Wp,
                                                     int copies_per_chunk) {
    if (blockIdx.x >= G_CHUNKS * 16) {
        int widx = (blockIdx.x - G_CHUNKS * 16) * 256 + threadIdx.x;
        for (int j = widx; j < D_DIM * 64; j += 8 * 256) {
            int d = j >> 6;
            int p = j & 63;
            Wp[j] = (p < P_DIM) ? W[d * P_DIM + p] : 0.0f;
        }
        return;
    }
    const int chunk = blockIdx.x >> 4;             // 0..7
    const int idx   = (blockIdx.x & 15) * 256 + threadIdx.x;  // 0..4095
    const double* src = partials + (size_t)chunk * copies_per_chunk * 4096;
    double s = 0.0;
    for (int c = 0; c < copies_per_chunk; c++)
        s += src[(size_t)c * 4096 + idx];
    G8[(size_t)chunk * 4096 + idx] = s;
}

// ---------------------------------------------------------------------------
// K2: per-channel stats (unchanged).
// ---------------------------------------------------------------------------
__global__ __launch_bounds__(64) void stats_kernel(const double* __restrict__ G,
                                                   const float* __restrict__ W,
                                                   const float* __restrict__ gamma,
                                                   const float* __restrict__ beta,
                                                   float* __restrict__ stats) {
    const int d = blockIdx.x;    // 0..127
    const int p = threadIdx.x;   // 0..63
    __shared__ float sW[64];
    sW[p] = (p < P_DIM) ? W[d * P_DIM + p] : 0.0f;
    __syncthreads();

    double inner = 0.0;
#pragma unroll
    for (int c = 0; c < G_CHUNKS; c++) {
        const double* Gr = G + (size_t)c * (64 * 64) + p * 64;
        for (int q = 0; q < 64; q++) inner += Gr[q] * (double)sW[q];
    }

    double contrib = (double)sW[p] * inner;   // row 63 has w=0 -> no effect
    double ex2M = contrib;
#pragma unroll
    for (int off = 32; off > 0; off >>= 1) ex2M += __shfl_down(ex2M, off, 64);
    double meanM = __shfl(inner, 63, 64);     // ones-row dot W_d = colsum . W_d

    if (p == 0) {
        double mean = meanM / (double)M_ROWS;
        double ex2  = ex2M  / (double)M_ROWS;
        double var  = ex2 - mean * mean;
        float varf  = (float)var;
        float vpe   = varf + 1e-5f;                 // ref: fp32 var + fp32 eps
        float invstd = (float)(1.0 / sqrt((double)vpe));
        stats[d * 4 + 0] = (float)mean;
        stats[d * 4 + 1] = invstd;
        stats[d * 4 + 2] = gamma[d];
        stats[d * 4 + 3] = beta[d];
    }
}

// ---------------------------------------------------------------------------
// K3 r14 (= r13 resubmitted after container-side failure; no kernel defect
// found in audit).  r12 decomposition (lane=row, wave=channel-chunk, W off
// the LDS pipe) with the two r12 failures fixed:
//  (1) REGISTER FOOTPRINT: 16 ch/wave (512-thread block, 8 waves, d0=wv*16)
//      -> acc[4][16]=64 VGPR; launch_bounds(512,4) -> 2 blocks/CU, VGPR cap
//      128.  pq loop unroll-4 caps W-load hoisting per scheduling region.
//      (r12: acc 128 + 32 hoisted w float4 blew the budget -> acc spilled
//      to scratch, VGPR=88, 392us.)
//  (2) STORES: spike overwrites acc in place; stores t-outer/jq-inner so 4
//      consecutive b128 complete each 64B sector; PLAIN stores (r12's
//      nontemporal + jq-outer scatter defeated L2 merge: 295MB vs 134MB).
// x staged once: sx[t][row][64], 16B XOR swizzle (quad ^= row&7) ->
// conflict-free ds_read_b128; 64 x-reads feed 4096 FMA instr per wave.
// p padded to 64 with x=0,w=0 (exact no-op) -> fmaf chain ascending p=0..62
// -> h bitwise identical (r12 passed absmax=0.0 with same pad).
// ---------------------------------------------------------------------------
__global__ __launch_bounds__(512, 4) void lif_kernel(const float* __restrict__ x,
                                                     const float* __restrict__ Wp,
                                                     const float* __restrict__ stats,
                                                     float* __restrict__ out) {
    __shared__ __align__(16) float sx[T_STEPS * 64 * 64];   // 65536 B
    const int tid = threadIdx.x;
    const int lane = tid & 63;

    // zero the padded column c=63 (quad 15, swizzled) for all (t, r)
    if (tid < 256) {
        int t = tid >> 6, r = tid & 63;
        sx[(t * 64 + r) * 64 + (((15 ^ (r & 7)) << 2) | 3)] = 0.0f;
    }

    // stage x rows r0..r0+63, 4 timesteps: 128 threads per t-segment,
    // coalesced b128 + swizzled scatter
    const int r0 = blockIdx.x * 64;
    {
        const int seg = tid >> 7;      // 0..3
        const int sub = tid & 127;
        const v4f* src = (const v4f*)(x + ((size_t)seg * R_ROWS + r0) * P_DIM);
#pragma unroll
        for (int kk = 0; kk < 8; kk++) {
            int k = sub + kk * 128;    // < 1024; 1008 = 64*63/4 valid
            v4f v;
            if (k < 1008) v = __builtin_nontemporal_load(&src[k]);
            if (k < 1008) {
                int flat = k * 4;
#pragma unroll
                for (int e = 0; e < 4; e++) {
                    int f = flat + e;
                    int r = f / 63;
                    int c = f - r * 63;
                    sx[(seg * 64 + r) * 64 + ((((c >> 2) ^ (r & 7)) << 2) | (c & 3))] = v[e];
                }
            }
        }
    }
    __syncthreads();

    // wave-uniform channel chunk of 16
    const int wv = __builtin_amdgcn_readfirstlane(tid >> 6);   // 0..7
    const int d0 = wv * 16;
    const float* __restrict__ wbase = Wp + (size_t)d0 * 64;
    const int s7 = lane & 7;

    float acc[T_STEPS][16];
#pragma unroll
    for (int t = 0; t < T_STEPS; t++)
#pragma unroll
        for (int c = 0; c < 16; c++) acc[t][c] = 0.0f;

    // main loop over 16 p-quads (quad 15 = exact no-op pad); unroll-4 chunks
#pragma unroll 4
    for (int pq = 0; pq < 16; pq++) {
        float4 xq[T_STEPS];
#pragma unroll
        for (int t = 0; t < T_STEPS; t++)
            xq[t] = *(const float4*)&sx[(t * 64 + lane) * 64 + ((pq ^ s7) << 2)];

#pragma unroll
        for (int c = 0; c < 16; c++) {
            float4 w = *(const float4*)&wbase[c * 64 + (pq << 2)];  // uniform
            const float* wa = (const float*)&w;
#pragma unroll
            for (int pp = 0; pp < 4; pp++) {         // ascending p within quad
                const float wval = wa[pp];
#pragma unroll
                for (int t = 0; t < T_STEPS; t++) {
                    const float xval = ((const float*)&xq[t])[pp];
                    acc[t][c] = fmaf(xval, wval, acc[t][c]);
                }
            }
        }
    }

    // epilogue: BN affine (ref op order) + LIF scan, spike overwrites acc
    const int rowg = r0 + lane;
#pragma unroll
    for (int c = 0; c < 16; c++) {
        float4 st = ((const float4*)stats)[d0 + c];  // mean, invstd, gamma, beta
        float v = 0.0f;
#pragma unroll
        for (int t = 0; t < T_STEPS; t++) {
            float hn = (acc[t][c] - st.x) * st.y;
            hn = hn * st.z;
            hn = hn + st.w;
            v = v + (hn - v) * 0.5f;           // == v + (x-v)/2, exact
            float s = (v >= 1.0f) ? 1.0f : 0.0f;  // (v-1>=0) sign-exact
            acc[t][c] = s;
            if (s != 0.0f) v = 0.0f;           // hard reset
        }
    }
    // stores: t-outer, jq-inner -> 4 consecutive b128 fill each 64B sector;
    // plain stores so L2 write-allocate merges lanes' 512B-strided 16B pieces
#pragma unroll
    for (int t = 0; t < T_STEPS; t++) {
        float* obase = &out[((size_t)t * R_ROWS + rowg) * D_DIM + d0];
#pragma unroll
        for (int jq = 0; jq < 4; jq++) {
            v4f o = {acc[t][jq * 4 + 0], acc[t][jq * 4 + 1],
                     acc[t][jq * 4 + 2], acc[t][jq * 4 + 3]};
            *(v4f*)&obase[jq * 4] = o;
        }
    }
}

// ---------------------------------------------------------------------------
extern "C" void kernel_launch(void* const* d_in, const int* in_sizes, int n_in,
                              void* d_out, int out_size, void* d_ws, size_t ws_size,
                              hipStream_t stream) {
    const float* x     = (const float*)d_in[0];
    const float* W     = (const float*)d_in[1];
    const float* gamma = (const float*)d_in[2];
    const float* beta  = (const float*)d_in[3];
    float* out = (float*)d_out;

    // pick partial count by available workspace (power of 2, 64..512)
    const size_t fixed = (size_t)G_CHUNKS * 4096 * 8 + 2048 + 32768 + 4096;
    int nparts = 512;
    while (nparts > 64 && (size_t)nparts * 4096 * 8 + fixed > ws_size) nparts >>= 1;
    const int tiles_per_block = TILES_TOTAL / nparts;

    double* partials = (double*)d_ws;
    double* G8       = (double*)((char*)d_ws + (size_t)nparts * 4096 * 8);
    float*  stats    = (float*)((char*)G8 + (size_t)G_CHUNKS * 4096 * 8);
    float*  Wp       = (float*)((char*)stats + 2048);

    gram_kernel<<<nparts, 256, 0, stream>>>(x, partials, tiles_per_block);
    reduce_kernel<<<G_CHUNKS * 16 + 8, 256, 0, stream>>>(partials, G8, W, Wp,
                                                         nparts / G_CHUNKS);
    stats_kernel<<<D_DIM, 64, 0, stream>>>(G8, W, gamma, beta, stats);
    lif_kernel<<<R_ROWS / 64, 512, 0, stream>>>(x, Wp, stats, out);
}